// Round 10
// baseline (110.750 us; speedup 1.0000x reference)
//
#include <hip/hip_runtime.h>

// MMD loss: source (4096,256) fp32, target (4096,256) fp32 -> scalar fp32.
// bandwidth closed form: sum(l2) = 2n*S - 2*||m||^2 (relu effect negligible).
// NO fences, NO atomics: visibility via kernel dispatch boundaries.
// Ledger: R1=99.2. R2: agent-atomics L2 wb/inv storm (-28) => k_main is
//   HIGHLY sensitive to XCD-L2 residency of panel re-reads. R3: BK=32 dbuf
//   full-drain (-2.7). R4: occupancy-5 VGPR spills (-27). R6: tiled tbT
//   NEUTRAL. R7: persistent+prefetch NEUTRAL. R8: counted-vmcnt NEUTRAL.
//   R9: infra failure (container died twice) — identical source resubmitted
//   (same precedent as R5: audit found no kernel defect).
// R9 change (single variable vs R8): TJ-BANDED tile order within each XCD
//   chunk. Bands of 16 tj-columns; per band walk all chunk rows. Working
//   set ~5 A-panels + 16 B-panels (~1.3MB; in-flight window ~2.6MB) fits
//   XCD L2 -> staging becomes L2-hit after first touch. part[] slot = global
//   row-major rank -> k_final unchanged.
//   k_prep (256 blk): fp32->bf16 tbT[tile][kc8][128][4 slots], sq[], partials
//   k_bw   (1 blk)  : reduce partials -> coef = log2(e)/(16*bw)
//   k_main (2080 blk): 128x128 bf16 MFMA GEMM, BK=32 dbuf counted-vmcnt,
//                      banded XCD-chunk order, packed-f32 epilogue
//   k_final(1 blk)  : double-precision sum of part[] -> out

#define NROWS 8192
#define BHALF 4096
#define DDIM  256
#define TILE  128
#define BK    32
#define NTILE 64
#define NBLK  2080   // NTILE*(NTILE+1)/2 = 8 * 260 -> bijective XCD chunks
#define BANDW 16

typedef __attribute__((ext_vector_type(8))) short bf16x8;
typedef __attribute__((ext_vector_type(4))) float f32x4;
typedef __attribute__((ext_vector_type(2))) float f32x2;
typedef __attribute__((ext_vector_type(4))) unsigned short u16x4;

struct Ws {
  float coef;
  float Spart[256];
  float cpart[256][256];   // per-block column-sum partials
  float sq[NROWS];
  float part[NBLK];
};

__device__ __forceinline__ unsigned short f2bf(float x) {
  unsigned int u = __builtin_bit_cast(unsigned int, x);
  return (unsigned short)((u + 0x7fffu + ((u >> 16) & 1u)) >> 16);
}

__device__ __forceinline__ const float* row_ptr(const float* src, const float* tgt, int i) {
  return (i < BHALF) ? (src + (size_t)i * DDIM) : (tgt + (size_t)(i - BHALF) * DDIM);
}

// Row-major triangular unrank: idx -> (ti, tj), ti<=tj<64.
__device__ __forceinline__ void derive_tile(int idx, int& ti_o, int& tj_o) {
  int t = (int)((129.0 - sqrt(129.0 * 129.0 - 8.0 * (double)idx)) * 0.5);
  while (64 * (t + 1) - ((t + 1) * t) / 2 <= idx) ++t;
  while (64 * t - (t * (t - 1)) / 2 > idx) --t;
  ti_o = t;
  tj_o = t + (idx - (64 * t - (t * (t - 1)) / 2));
}

// 256 blocks x 256 threads; 8 rows per wave. Partials only — no atomics.
// tbT: [tile][kc8 0..7][128 rows][32 shorts]. Slot s (8-short unit) of row
// rl holds logical chunk s^((rl>>1)&3) of K-window kc8.
__global__ __launch_bounds__(256) void k_prep(const float* __restrict__ src,
                                              const float* __restrict__ tgt,
                                              Ws* __restrict__ ws,
                                              unsigned short* __restrict__ tb,
                                              int conv) {
  __shared__ float cls[4][256];
  __shared__ float sred[4];
  int tid = threadIdx.x, wave = tid >> 6, lane = tid & 63;
  int row0 = blockIdx.x * 32 + wave * 8;
  float c0 = 0.f, c1 = 0.f, c2 = 0.f, c3 = 0.f;
  float s[8];
  #pragma unroll
  for (int r = 0; r < 8; ++r) {
    const float4* rp = (const float4*)row_ptr(src, tgt, row0 + r);
    float4 x = rp[lane];
    if (conv) {
      u16x4 b = { f2bf(x.x), f2bf(x.y), f2bf(x.z), f2bf(x.w) };
      int rg = row0 + r;
      int t = rg >> 7, rl = rg & 127;
      int cg = lane >> 1;
      int k8 = cg >> 2, cwp = cg & 3;
      int slot = cwp ^ ((rl >> 1) & 3);
      *(u16x4*)&tb[((size_t)(t * 8 + k8) * 128 + rl) * 32 + slot * 8 + (lane & 1) * 4] = b;
    }
    c0 += x.x; c1 += x.y; c2 += x.z; c3 += x.w;
    s[r] = x.x * x.x + x.y * x.y + x.z * x.z + x.w * x.w;
  }
  #pragma unroll
  for (int off = 32; off > 0; off >>= 1) {
    #pragma unroll
    for (int r = 0; r < 8; ++r) s[r] += __shfl_xor(s[r], off);
  }
  if (lane == 0) {
    float Sw = 0.f;
    #pragma unroll
    for (int r = 0; r < 8; ++r) { ws->sq[row0 + r] = s[r]; Sw += s[r]; }
    sred[wave] = Sw;
  }
  cls[wave][lane * 4 + 0] = c0;
  cls[wave][lane * 4 + 1] = c1;
  cls[wave][lane * 4 + 2] = c2;
  cls[wave][lane * 4 + 3] = c3;
  __syncthreads();
  ws->cpart[blockIdx.x][tid] = cls[0][tid] + cls[1][tid] + cls[2][tid] + cls[3][tid];
  if (tid == 0) ws->Spart[blockIdx.x] = sred[0] + sred[1] + sred[2] + sred[3];
}

// 1 block x 256 threads: partials -> coef. Accumulation ORDER identical to
// the original serial loop -> coef bit-identical.
__global__ __launch_bounds__(256) void k_bw(Ws* __restrict__ ws) {
  __shared__ float redm[4], reds[4];
  int tid = threadIdx.x, wave = tid >> 6, lane = tid & 63;
  float mc = 0.f;
  for (int b0 = 0; b0 < 256; b0 += 16) {
    float v[16];
    #pragma unroll
    for (int j = 0; j < 16; ++j) v[j] = ws->cpart[b0 + j][tid];
    #pragma unroll
    for (int j = 0; j < 16; ++j) mc += v[j];
  }
  float p = mc * mc;
  float sp = ws->Spart[tid];
  #pragma unroll
  for (int off = 32; off > 0; off >>= 1) {
    p  += __shfl_xor(p, off);
    sp += __shfl_xor(sp, off);
  }
  if (lane == 0) { redm[wave] = p; reds[wave] = sp; }
  __syncthreads();
  if (tid == 0) {
    float msq = redm[0] + redm[1] + redm[2] + redm[3];
    float S   = reds[0] + reds[1] + reds[2] + reds[3];
    double n = (double)NROWS;
    double sum_l2 = 2.0 * n * (double)S - 2.0 * (double)msq;
    double bw = sum_l2 / (n * n - n) / 4.0;      // / KERNEL_MUL^(KERNEL_NUM/2)
    ws->coef = (float)(1.4426950408889634 / (16.0 * bw)); // log2(e)/(16*bw)
  }
}

// Stage one BK=32 phase from tbT: per wave 2x(A,B) loads of 1 KB, contiguous.
__device__ __forceinline__ void stage32(const unsigned short* gA,
                                        const unsigned short* gB,
                                        unsigned short* lA, unsigned short* lB,
                                        int kcs) {
  #pragma unroll
  for (int t = 0; t < 2; ++t) {
    __builtin_amdgcn_global_load_lds(
        (const __attribute__((address_space(1))) void*)(gA + (size_t)kcs * 4096 + t * 512),
        (__attribute__((address_space(3))) void*)(lA + t * 512), 16, 0, 0);
    __builtin_amdgcn_global_load_lds(
        (const __attribute__((address_space(1))) void*)(gB + (size_t)kcs * 4096 + t * 512),
        (__attribute__((address_space(3))) void*)(lB + t * 512), 16, 0, 0);
  }
}

// NBLK blocks, 4 waves, 128x128 tile, BK=32 dbuf, counted vmcnt.
// Tile selection: XCD chunk c = bid&7 owns global ranks [c*260, c*260+260).
// Within the chunk, tiles are visited in TJ-BANDED order (bands of 16
// columns; per band, walk the chunk's rows) so the ~16 B-panels + ~5
// A-panels of a band stay resident in the XCD's 4MiB L2.
template <int FAST>
__global__ __launch_bounds__(256, 4) void k_main(const unsigned short* __restrict__ tb,
                                                 const float* __restrict__ src,
                                                 const float* __restrict__ tgt,
                                                 Ws* __restrict__ ws) {
  int bid = blockIdx.x;
  int c = bid & 7, k = bid >> 3;               // chunk, within-chunk rank 0..259
  int g0 = c * (NBLK / 8);
  int ti0, tjs; derive_tile(g0, ti0, tjs);           // chunk start (partial row)
  int ti1, tje; derive_tile(g0 + (NBLK / 8) - 1, ti1, tje); // chunk end
  int ti = 0, tj = 0;
  {
    int kr = k;
    bool done = false;
    for (int b = 0; b < 64 / BANDW && !done; ++b) {
      int blo = b * BANDW, bhi = blo + (BANDW - 1);
      for (int r = ti0; r <= ti1; ++r) {
        int lo = (r == ti0) ? tjs : r;         // first row may start mid-row
        int hi = (r == ti1) ? tje : 63;        // last row may end early
        int l2 = lo > blo ? lo : blo;
        int h2 = hi < bhi ? hi : bhi;
        int cnt = h2 - l2 + 1;
        if (cnt > 0) {
          if (kr < cnt) { ti = r; tj = l2 + kr; done = true; break; }
          kr -= cnt;
        }
      }
    }
  }

  __shared__ __align__(16) unsigned short As[2][TILE * BK];
  __shared__ __align__(16) unsigned short Bs[2][TILE * BK];
  __shared__ float wsum[4];

  int tid = threadIdx.x;
  int wave = tid >> 6, lane = tid & 63;
  int wm = wave >> 1, wn = wave & 1;           // 2x2 wave grid, 64x64 each
  int lr = lane & 15, q = lane >> 4;
  int Ib = ti * TILE, Jb = tj * TILE;

  f32x4 zero = {0.f, 0.f, 0.f, 0.f};
  f32x4 acc[4][4];
  #pragma unroll
  for (int m = 0; m < 4; ++m)
    #pragma unroll
    for (int n = 0; n < 4; ++n) acc[m][n] = zero;

  // Read-side swizzled chunk offset (shorts): chunk q at slot q^((row>>1)&3).
  const int coff = ((q ^ ((lr >> 1) & 3)) << 3);

  if (FAST) {
    const unsigned short* gA = tb + (size_t)ti * 32768 + wave * 1024 + lane * 8;
    const unsigned short* gB = tb + (size_t)tj * 32768 + wave * 1024 + lane * 8;
    unsigned short* lA0 = &As[0][wave * 1024];
    unsigned short* lB0 = &Bs[0][wave * 1024];
    unsigned short* lA1 = &As[1][wave * 1024];
    unsigned short* lB1 = &Bs[1][wave * 1024];

    stage32(gA, gB, lA0, lB0, 0);              // prologue: 4 loads in flight
    #pragma unroll
    for (int kcs = 0; kcs < 8; ++kcs) {
      if (kcs < 7) {
        // issue next phase (4 more loads -> 8 outstanding), then wait for
        // ONLY the previous phase's 4 (issued one full compute-phase ago).
        stage32(gA, gB, ((kcs + 1) & 1) ? lA1 : lA0,
                        ((kcs + 1) & 1) ? lB1 : lB0, kcs + 1);
        asm volatile("s_waitcnt vmcnt(4)" ::: "memory");
      } else {
        asm volatile("s_waitcnt vmcnt(0)" ::: "memory");
      }
      __builtin_amdgcn_s_barrier();            // all waves' phase-kcs data in LDS
      const unsigned short* Ab = As[kcs & 1];
      const unsigned short* Bb = Bs[kcs & 1];
      bf16x8 af[4], bfr[4];
      #pragma unroll
      for (int m = 0; m < 4; ++m)
        af[m] = *(const bf16x8*)&Ab[(wm * 64 + m * 16 + lr) * BK + coff];
      #pragma unroll
      for (int n = 0; n < 4; ++n)
        bfr[n] = *(const bf16x8*)&Bb[(wn * 64 + n * 16 + lr) * BK + coff];
      #pragma unroll
      for (int m = 0; m < 4; ++m)
        #pragma unroll
        for (int n = 0; n < 4; ++n)
          acc[m][n] = __builtin_amdgcn_mfma_f32_16x16x32_bf16(af[m], bfr[n], acc[m][n], 0, 0, 0);
      __builtin_amdgcn_s_barrier();            // reads done before buffer reuse
    }
  } else {
    // Fallback: synchronous reg-staging from fp32 with in-kernel bf16 convert.
    int row = tid >> 1, h = tid & 1;
    int fsw = (row >> 1) & 3;
    const float4* rpA = (const float4*)row_ptr(src, tgt, Ib + row);
    const float4* rpB = (const float4*)row_ptr(src, tgt, Jb + row);
    #pragma unroll
    for (int kcs = 0; kcs < 8; ++kcs) {
      if (kcs) __syncthreads();
      unsigned short* lA = As[kcs & 1];
      unsigned short* lB = Bs[kcs & 1];
      #pragma unroll
      for (int cc = 0; cc < 2; ++cc) {
        int cx = h * 2 + cc;
        int slot = cx ^ fsw;
        float4 v0 = rpA[kcs * 8 + cx * 2], v1 = rpA[kcs * 8 + cx * 2 + 1];
        u16x4 a0 = { f2bf(v0.x), f2bf(v0.y), f2bf(v0.z), f2bf(v0.w) };
        u16x4 a1 = { f2bf(v1.x), f2bf(v1.y), f2bf(v1.z), f2bf(v1.w) };
        *(u16x4*)&lA[row * BK + slot * 8]     = a0;
        *(u16x4*)&lA[row * BK + slot * 8 + 4] = a1;
        float4 w0 = rpB[kcs * 8 + cx * 2], w1 = rpB[kcs * 8 + cx * 2 + 1];
        u16x4 b0 = { f2bf(w0.x), f2bf(w0.y), f2bf(w0.z), f2bf(w0.w) };
        u16x4 b1 = { f2bf(w1.x), f2bf(w1.y), f2bf(w1.z), f2bf(w1.w) };
        *(u16x4*)&lB[row * BK + slot * 8]     = b0;
        *(u16x4*)&lB[row * BK + slot * 8 + 4] = b1;
      }
      __syncthreads();
      const unsigned short* Ab = As[kcs & 1];
      const unsigned short* Bb = Bs[kcs & 1];
      bf16x8 af[4], bfr[4];
      #pragma unroll
      for (int m = 0; m < 4; ++m)
        af[m] = *(const bf16x8*)&Ab[(wm * 64 + m * 16 + lr) * BK + coff];
      #pragma unroll
      for (int n = 0; n < 4; ++n)
        bfr[n] = *(const bf16x8*)&Bb[(wn * 64 + n * 16 + lr) * BK + coff];
      #pragma unroll
      for (int m = 0; m < 4; ++m)
        #pragma unroll
        for (int n = 0; n < 4; ++n)
          acc[m][n] = __builtin_amdgcn_mfma_f32_16x16x32_bf16(af[m], bfr[n], acc[m][n], 0, 0, 0);
    }
  }

  // Epilogue operand loads AFTER the K-loop (keeps hot-loop VGPRs low).
  float coef = ws->coef;
  float coef2 = 2.f * coef;
  int ibase = Ib + wm * 64;
  int jbase = Jb + wn * 64;
  float nscj[4];
  f32x2 nsci01[4], nsci23[4];
  #pragma unroll
  for (int n = 0; n < 4; ++n) nscj[n] = -ws->sq[jbase + n * 16 + lr] * coef;
  #pragma unroll
  for (int m = 0; m < 4; ++m) {
    nsci01[m] = f32x2{ -ws->sq[ibase + m * 16 + q * 4 + 0] * coef,
                       -ws->sq[ibase + m * 16 + q * 4 + 1] * coef };
    nsci23[m] = f32x2{ -ws->sq[ibase + m * 16 + q * 4 + 2] * coef,
                       -ws->sq[ibase + m * 16 + q * 4 + 3] * coef };
  }

  // Packed epilogue: arg = 2g*coef - (sqi+sqj)*coef; K = t+t^2+t^4+t^8+t^16.
  const f32x2 c2v = { coef2, coef2 };
  f32x2 accA = {0.f, 0.f}, accB = {0.f, 0.f};
  f32x2 accC = {0.f, 0.f}, accD = {0.f, 0.f};
  #pragma unroll
  for (int m = 0; m < 4; ++m) {
    #pragma unroll
    for (int n = 0; n < 4; ++n) {
      f32x4 g = acc[m][n];
      f32x2 bj = { nscj[n], nscj[n] };
      f32x2 b01 = nsci01[m] + bj;
      f32x2 b23 = nsci23[m] + bj;
      f32x2 a01 = f32x2{g[0], g[1]} * c2v + b01;
      f32x2 a23 = f32x2{g[2], g[3]} * c2v + b23;
      f32x2 t0, t1;
      t0.x = __builtin_amdgcn_exp2f(a01.x); t0.y = __builtin_amdgcn_exp2f(a01.y);
      t1.x = __builtin_amdgcn_exp2f(a23.x); t1.y = __builtin_amdgcn_exp2f(a23.y);
      f32x2 p0 = t0 * t0, p1 = t1 * t1;
      f32x2 q0 = p0 * p0, q1 = p1 * p1;
      f32x2 r0v = q0 * q0, r1v = q1 * q1;
      accA += t0 + p0;
      accB += q0 + r0v;
      accA = r0v * r0v + accA;                 // + t^16
      accC += t1 + p1;
      accD += q1 + r1v;
      accC = r1v * r1v + accC;
    }
  }
  float lsum = (accA.x + accA.y) + (accB.x + accB.y)
             + (accC.x + accC.y) + (accD.x + accD.y);
  #pragma unroll
  for (int off = 32; off > 0; off >>= 1) lsum += __shfl_xor(lsum, off);
  if (lane == 0) wsum[wave] = lsum;
  __syncthreads();
  if (tid == 0) {
    float tot = wsum[0] + wsum[1] + wsum[2] + wsum[3];
    float sA = (ti < 32) ? 1.f : -1.f;         // B=4096 = 32 tiles of 128
    float sB = (tj < 32) ? 1.f : -1.f;
    float fac = sA * sB * ((ti == tj) ? 1.f : 2.f);
    int slot = 64 * ti - (ti * (ti - 1)) / 2 + (tj - ti); // global row-major rank
    ws->part[slot] = fac * tot;                // plain store — NO fence/atomic
  }
}

// 1 block x 256 threads: double-precision reduce of part[] -> out scalar.
__global__ __launch_bounds__(256) void k_final(const Ws* __restrict__ ws,
                                               float* __restrict__ out) {
  __shared__ double red[4];
  int tid = threadIdx.x, wave = tid >> 6, lane = tid & 63;
  double s = 0.0;
  for (int i = tid; i < NBLK; i += 256) s += (double)ws->part[i];
  #pragma unroll
  for (int off = 32; off > 0; off >>= 1) s += __shfl_xor(s, off);
  if (lane == 0) red[wave] = s;
  __syncthreads();
  if (tid == 0)
    out[0] = (float)((red[0] + red[1] + red[2] + red[3]) /
                     ((double)BHALF * (double)BHALF));
}

extern "C" void kernel_launch(void* const* d_in, const int* in_sizes, int n_in,
                              void* d_out, int out_size, void* d_ws, size_t ws_size,
                              hipStream_t stream) {
  const float* src = (const float*)d_in[0];
  const float* tgt = (const float*)d_in[1];
  Ws* ws = (Ws*)d_ws;
  float* out = (float*)d_out;

  size_t wsoff = (sizeof(Ws) + 255) & ~(size_t)255;
  size_t need = wsoff + (size_t)NROWS * DDIM * 2;
  bool fast = ws_size >= need;
  unsigned short* tb = fast ? (unsigned short*)((char*)d_ws + wsoff) : nullptr;

  hipLaunchKernelGGL(k_prep, dim3(256), dim3(256), 0, stream, src, tgt, ws, tb,
                     fast ? 1 : 0);
  hipLaunchKernelGGL(k_bw, dim3(1), dim3(256), 0, stream, ws);
  if (fast)
    hipLaunchKernelGGL((k_main<1>), dim3(NBLK), dim3(256), 0, stream, tb, src, tgt, ws);
  else
    hipLaunchKernelGGL((k_main<0>), dim3(NBLK), dim3(256), 0, stream, tb, src, tgt, ws);
  hipLaunchKernelGGL(k_final, dim3(1), dim3(256), 0, stream, ws, out);
}

// Round 11
// 98.222 us; speedup vs baseline: 1.1275x; 1.1275x over previous
//
#include <hip/hip_runtime.h>

// MMD loss: source (4096,256) fp32, target (4096,256) fp32 -> scalar fp32.
// bandwidth closed form: sum(l2) = 2n*S - 2*||m||^2 (relu effect negligible).
// NO fences, NO atomics: visibility via kernel dispatch boundaries.
// Ledger: R1=99.2, R8=101.5 (counted-vmcnt neutral). R2: agent-atomics (-28).
//   R4: VGPR spills (-27). R6/R7/R8 structural: NEUTRAL. R10: banding (-9,
//   dropped) BUT first clean k_main profile: 43.7us, Mfma 14%, VALU 22%,
//   HBM 9%, occupancy 21.5% (~1.7/4 blocks/CU resident) => latency-bound,
//   block latency ~9us, residency churn with 2080 short blocks.
// R11 change: 256x128 tiles, 512 thr (8 waves), 1056 blocks (=8x132).
//   Same per-wave shape (64x64 out, 64 AGPR) -> no register cliff
//   (launch_bounds(512,4) = 2 blocks/CU = same 4 waves/SIMD). Half the
//   blocks, -24% staged bytes (A shared by 2 j-tiles), 3 loads/wave/phase,
//   sync+epilogue amortized 2x. part[] keeps the 2080 row-major ranks
//   (top half bit-identical to old (2I,tj) block; (2I,2I+1) via symmetric
//   transpose at tj==2I; block(I,2I+1) top is dead).
//   k_prep (256 blk): fp32->bf16 tbT[tile][kc8][128][4 slots], sq[], partials
//   k_bw   (1 blk)  : reduce partials -> coef = log2(e)/(16*bw)
//   k_main (1056 blk x 512): 256x128 bf16 MFMA GEMM, BK=32 dbuf counted
//                      vmcnt, XCD-chunked, packed-f32 epilogue
//   k_final(1 blk)  : double-precision sum of part[2080] -> out

#define NROWS 8192
#define BHALF 4096
#define DDIM  256
#define BK    32
#define NTILE 64     // 128-row tiles
#define NBLK  2080   // 128x128 pair count (part[] ranks)
#define NBLK2 1056   // 256x128 blocks = sum_{I<32}(64-2I) = 8*132

typedef __attribute__((ext_vector_type(8))) short bf16x8;
typedef __attribute__((ext_vector_type(4))) float f32x4;
typedef __attribute__((ext_vector_type(2))) float f32x2;
typedef __attribute__((ext_vector_type(4))) unsigned short u16x4;

struct Ws {
  float coef;
  float Spart[256];
  float cpart[256][256];   // per-block column-sum partials
  float sq[NROWS];
  float part[NBLK];
};

__device__ __forceinline__ unsigned short f2bf(float x) {
  unsigned int u = __builtin_bit_cast(unsigned int, x);
  return (unsigned short)((u + 0x7fffu + ((u >> 16) & 1u)) >> 16);
}

__device__ __forceinline__ const float* row_ptr(const float* src, const float* tgt, int i) {
  return (i < BHALF) ? (src + (size_t)i * DDIM) : (tgt + (size_t)(i - BHALF) * DDIM);
}

// 256 blocks x 256 threads; 8 rows per wave. Partials only — no atomics.
// tbT: [tile][kc8 0..7][128 rows][32 shorts]. Slot s (8-short unit) of row
// rl holds logical chunk s^((rl>>1)&3) of K-window kc8.
__global__ __launch_bounds__(256) void k_prep(const float* __restrict__ src,
                                              const float* __restrict__ tgt,
                                              Ws* __restrict__ ws,
                                              unsigned short* __restrict__ tb,
                                              int conv) {
  __shared__ float cls[4][256];
  __shared__ float sred[4];
  int tid = threadIdx.x, wave = tid >> 6, lane = tid & 63;
  int row0 = blockIdx.x * 32 + wave * 8;
  float c0 = 0.f, c1 = 0.f, c2 = 0.f, c3 = 0.f;
  float s[8];
  #pragma unroll
  for (int r = 0; r < 8; ++r) {
    const float4* rp = (const float4*)row_ptr(src, tgt, row0 + r);
    float4 x = rp[lane];
    if (conv) {
      u16x4 b = { f2bf(x.x), f2bf(x.y), f2bf(x.z), f2bf(x.w) };
      int rg = row0 + r;
      int t = rg >> 7, rl = rg & 127;
      int cg = lane >> 1;
      int k8 = cg >> 2, cwp = cg & 3;
      int slot = cwp ^ ((rl >> 1) & 3);
      *(u16x4*)&tb[((size_t)(t * 8 + k8) * 128 + rl) * 32 + slot * 8 + (lane & 1) * 4] = b;
    }
    c0 += x.x; c1 += x.y; c2 += x.z; c3 += x.w;
    s[r] = x.x * x.x + x.y * x.y + x.z * x.z + x.w * x.w;
  }
  #pragma unroll
  for (int off = 32; off > 0; off >>= 1) {
    #pragma unroll
    for (int r = 0; r < 8; ++r) s[r] += __shfl_xor(s[r], off);
  }
  if (lane == 0) {
    float Sw = 0.f;
    #pragma unroll
    for (int r = 0; r < 8; ++r) { ws->sq[row0 + r] = s[r]; Sw += s[r]; }
    sred[wave] = Sw;
  }
  cls[wave][lane * 4 + 0] = c0;
  cls[wave][lane * 4 + 1] = c1;
  cls[wave][lane * 4 + 2] = c2;
  cls[wave][lane * 4 + 3] = c3;
  __syncthreads();
  ws->cpart[blockIdx.x][tid] = cls[0][tid] + cls[1][tid] + cls[2][tid] + cls[3][tid];
  if (tid == 0) ws->Spart[blockIdx.x] = sred[0] + sred[1] + sred[2] + sred[3];
}

// 1 block x 256 threads: partials -> coef. Accumulation ORDER identical to
// the original serial loop -> coef bit-identical.
__global__ __launch_bounds__(256) void k_bw(Ws* __restrict__ ws) {
  __shared__ float redm[4], reds[4];
  int tid = threadIdx.x, wave = tid >> 6, lane = tid & 63;
  float mc = 0.f;
  for (int b0 = 0; b0 < 256; b0 += 16) {
    float v[16];
    #pragma unroll
    for (int j = 0; j < 16; ++j) v[j] = ws->cpart[b0 + j][tid];
    #pragma unroll
    for (int j = 0; j < 16; ++j) mc += v[j];
  }
  float p = mc * mc;
  float sp = ws->Spart[tid];
  #pragma unroll
  for (int off = 32; off > 0; off >>= 1) {
    p  += __shfl_xor(p, off);
    sp += __shfl_xor(sp, off);
  }
  if (lane == 0) { redm[wave] = p; reds[wave] = sp; }
  __syncthreads();
  if (tid == 0) {
    float msq = redm[0] + redm[1] + redm[2] + redm[3];
    float S   = reds[0] + reds[1] + reds[2] + reds[3];
    double n = (double)NROWS;
    double sum_l2 = 2.0 * n * (double)S - 2.0 * (double)msq;
    double bw = sum_l2 / (n * n - n) / 4.0;      // / KERNEL_MUL^(KERNEL_NUM/2)
    ws->coef = (float)(1.4426950408889634 / (16.0 * bw)); // log2(e)/(16*bw)
  }
}

// Stage one BK=32 phase: per wave 2 A-loads + 1 B-load, 1 KB each, contiguous.
__device__ __forceinline__ void stage3(const unsigned short* gA,
                                       const unsigned short* gB,
                                       unsigned short* lA, unsigned short* lB,
                                       int kcs) {
  __builtin_amdgcn_global_load_lds(
      (const __attribute__((address_space(1))) void*)(gA + (size_t)kcs * 4096),
      (__attribute__((address_space(3))) void*)(lA), 16, 0, 0);
  __builtin_amdgcn_global_load_lds(
      (const __attribute__((address_space(1))) void*)(gA + (size_t)kcs * 4096 + 512),
      (__attribute__((address_space(3))) void*)(lA + 512), 16, 0, 0);
  __builtin_amdgcn_global_load_lds(
      (const __attribute__((address_space(1))) void*)(gB + (size_t)kcs * 4096),
      (__attribute__((address_space(3))) void*)(lB), 16, 0, 0);
}

// 1056 blocks x 512 thr (8 waves, 4m x 2n grid of 64x64). Block = 256-row
// band I x 128-col tile tj (tj in [2I,63]). XCD chunk c=bid&7 owns ranks
// [c*132, c*132+132), row-major within band order. BK=32 dbuf counted vmcnt.
__global__ __launch_bounds__(512, 4) void k_main2(const unsigned short* __restrict__ tb,
                                                  Ws* __restrict__ ws) {
  int bid = blockIdx.x;
  int r = (bid & 7) * (NBLK2 / 8) + (bid >> 3);
  // unrank: base(I) = I*(65-I) <= r < base(I+1)
  int I = (int)((65.0 - sqrt(4225.0 - 4.0 * (double)r)) * 0.5);
  while ((I + 1) * (65 - (I + 1)) <= r) ++I;
  while (I * (65 - I) > r) --I;
  int tj = 2 * I + (r - I * (65 - I));

  __shared__ __align__(16) unsigned short As[2][256 * BK];
  __shared__ __align__(16) unsigned short Bs[2][128 * BK];
  __shared__ float wsum[8];

  int tid = threadIdx.x;
  int wave = tid >> 6, lane = tid & 63;
  int wm = wave >> 1, wn = wave & 1;           // 4x2 wave grid, 64x64 each
  int lr = lane & 15, q = lane >> 4;
  const int coff = ((q ^ ((lr >> 1) & 3)) << 3);

  f32x4 zero = {0.f, 0.f, 0.f, 0.f};
  f32x4 acc[4][4];
  #pragma unroll
  for (int m = 0; m < 4; ++m)
    #pragma unroll
    for (int n = 0; n < 4; ++n) acc[m][n] = zero;

  // Staging: wave w covers A rows 32*(w&3)..+31 of 128-tile 2I+(w>>2)
  // (2 loads) and B rows 16w..16w+15 of tile tj (1 load).
  const unsigned short* gA = tb + (size_t)(2 * I + (wave >> 2)) * 32768
                                + (32 * (wave & 3)) * 32 + lane * 8;
  const unsigned short* gB = tb + (size_t)tj * 32768 + wave * 512 + lane * 8;
  unsigned short* lA0 = &As[0][((wave >> 2) * 128 + 32 * (wave & 3)) * 32];
  unsigned short* lB0 = &Bs[0][wave * 512];
  unsigned short* lA1 = &As[1][((wave >> 2) * 128 + 32 * (wave & 3)) * 32];
  unsigned short* lB1 = &Bs[1][wave * 512];

  stage3(gA, gB, lA0, lB0, 0);                 // prologue: 3 loads in flight
  #pragma unroll
  for (int kcs = 0; kcs < 8; ++kcs) {
    if (kcs < 7) {
      stage3(gA, gB, ((kcs + 1) & 1) ? lA1 : lA0,
                     ((kcs + 1) & 1) ? lB1 : lB0, kcs + 1);
      asm volatile("s_waitcnt vmcnt(3)" ::: "memory");  // prev phase's 3 done
    } else {
      asm volatile("s_waitcnt vmcnt(0)" ::: "memory");
    }
    __builtin_amdgcn_s_barrier();              // phase-kcs data in LDS (all waves)
    const unsigned short* Ab = As[kcs & 1];
    const unsigned short* Bb = Bs[kcs & 1];
    bf16x8 af[4], bfr[4];
    #pragma unroll
    for (int m = 0; m < 4; ++m)
      af[m] = *(const bf16x8*)&Ab[(wm * 64 + m * 16 + lr) * BK + coff];
    #pragma unroll
    for (int n = 0; n < 4; ++n)
      bfr[n] = *(const bf16x8*)&Bb[(wn * 64 + n * 16 + lr) * BK + coff];
    #pragma unroll
    for (int m = 0; m < 4; ++m)
      #pragma unroll
      for (int n = 0; n < 4; ++n)
        acc[m][n] = __builtin_amdgcn_mfma_f32_16x16x32_bf16(af[m], bfr[n], acc[m][n], 0, 0, 0);
    __builtin_amdgcn_s_barrier();              // reads done before buffer reuse
  }

  // Epilogue operand loads AFTER the K-loop.
  float coef = ws->coef;
  float coef2 = 2.f * coef;
  int ibase = I * 256 + wm * 64;
  int jbase = tj * 128 + wn * 64;
  float nscj[4];
  f32x2 nsci01[4], nsci23[4];
  #pragma unroll
  for (int n = 0; n < 4; ++n) nscj[n] = -ws->sq[jbase + n * 16 + lr] * coef;
  #pragma unroll
  for (int m = 0; m < 4; ++m) {
    nsci01[m] = f32x2{ -ws->sq[ibase + m * 16 + q * 4 + 0] * coef,
                       -ws->sq[ibase + m * 16 + q * 4 + 1] * coef };
    nsci23[m] = f32x2{ -ws->sq[ibase + m * 16 + q * 4 + 2] * coef,
                       -ws->sq[ibase + m * 16 + q * 4 + 3] * coef };
  }

  // Packed epilogue: arg = 2g*coef - (sqi+sqj)*coef; K = t+t^2+t^4+t^8+t^16.
  const f32x2 c2v = { coef2, coef2 };
  f32x2 accA = {0.f, 0.f}, accB = {0.f, 0.f};
  f32x2 accC = {0.f, 0.f}, accD = {0.f, 0.f};
  #pragma unroll
  for (int m = 0; m < 4; ++m) {
    #pragma unroll
    for (int n = 0; n < 4; ++n) {
      f32x4 g = acc[m][n];
      f32x2 bj = { nscj[n], nscj[n] };
      f32x2 b01 = nsci01[m] + bj;
      f32x2 b23 = nsci23[m] + bj;
      f32x2 a01 = f32x2{g[0], g[1]} * c2v + b01;
      f32x2 a23 = f32x2{g[2], g[3]} * c2v + b23;
      f32x2 t0, t1;
      t0.x = __builtin_amdgcn_exp2f(a01.x); t0.y = __builtin_amdgcn_exp2f(a01.y);
      t1.x = __builtin_amdgcn_exp2f(a23.x); t1.y = __builtin_amdgcn_exp2f(a23.y);
      f32x2 p0 = t0 * t0, p1 = t1 * t1;
      f32x2 q0 = p0 * p0, q1 = p1 * p1;
      f32x2 r0v = q0 * q0, r1v = q1 * q1;
      accA += t0 + p0;
      accB += q0 + r0v;
      accA = r0v * r0v + accA;                 // + t^16
      accC += t1 + p1;
      accD += q1 + r1v;
      accC = r1v * r1v + accC;
    }
  }
  float lsum = (accA.x + accA.y) + (accB.x + accB.y)
             + (accC.x + accC.y) + (accD.x + accD.y);
  #pragma unroll
  for (int off = 32; off > 0; off >>= 1) lsum += __shfl_xor(lsum, off);
  if (lane == 0) wsum[wave] = lsum;
  __syncthreads();
  if (tid == 0) {
    int t0 = 2 * I, t1 = 2 * I + 1;
    float sband = (I < 16) ? 1.f : -1.f;       // both 128-tiles share sign
    float sB = (tj < 32) ? 1.f : -1.f;
    float topv = wsum[0] + wsum[1] + wsum[2] + wsum[3];
    float botv = wsum[4] + wsum[5] + wsum[6] + wsum[7];
    // top half = pair (2I, tj); dead when tj==2I+1 (covered via symmetry)
    if (tj != t1) {
      float fac = (tj == t0) ? 1.f : 2.f;
      int rk = 64 * t0 - (t0 * (t0 - 1)) / 2 + (tj - t0);
      ws->part[rk] = fac * sband * sB * topv;
    }
    // bottom half: tj==t0 -> symmetric rep of (2I,2I+1); tj==t1 -> diag;
    // else pair (2I+1, tj)
    {
      float fac; int rk;
      if (tj == t0)      { fac = 2.f; rk = 64 * t0 - (t0 * (t0 - 1)) / 2 + 1; }
      else if (tj == t1) { fac = 1.f; rk = 64 * t1 - (t1 * (t1 - 1)) / 2; }
      else               { fac = 2.f; rk = 64 * t1 - (t1 * (t1 - 1)) / 2 + (tj - t1); }
      ws->part[rk] = fac * sband * sB * botv;
    }
  }
}

// Slow fallback (ws too small for tbT): R8's reg-staged 128x128 kernel.
__global__ __launch_bounds__(256, 4) void k_main_slow(const float* __restrict__ src,
                                                      const float* __restrict__ tgt,
                                                      Ws* __restrict__ ws) {
  int bid = blockIdx.x;
  int idx = (bid & 7) * (NBLK / 8) + (bid >> 3);
  int ti = (int)((129.0 - sqrt(129.0 * 129.0 - 8.0 * (double)idx)) * 0.5);
  while (64 * (ti + 1) - ((ti + 1) * ti) / 2 <= idx) ++ti;
  while (64 * ti - (ti * (ti - 1)) / 2 > idx) --ti;
  int tj = ti + (idx - (64 * ti - (ti * (ti - 1)) / 2));

  __shared__ __align__(16) unsigned short As[2][128 * BK];
  __shared__ __align__(16) unsigned short Bs[2][128 * BK];
  __shared__ float wsum[4];

  int tid = threadIdx.x;
  int wave = tid >> 6, lane = tid & 63;
  int wm = wave >> 1, wn = wave & 1;
  int lr = lane & 15, q = lane >> 4;
  int Ib = ti * 128, Jb = tj * 128;

  f32x4 zero = {0.f, 0.f, 0.f, 0.f};
  f32x4 acc[4][4];
  #pragma unroll
  for (int m = 0; m < 4; ++m)
    #pragma unroll
    for (int n = 0; n < 4; ++n) acc[m][n] = zero;

  const int coff = ((q ^ ((lr >> 1) & 3)) << 3);
  int row = tid >> 1, h = tid & 1;
  int fsw = (row >> 1) & 3;
  const float4* rpA = (const float4*)row_ptr(src, tgt, Ib + row);
  const float4* rpB = (const float4*)row_ptr(src, tgt, Jb + row);
  #pragma unroll
  for (int kcs = 0; kcs < 8; ++kcs) {
    if (kcs) __syncthreads();
    unsigned short* lA = As[kcs & 1];
    unsigned short* lB = Bs[kcs & 1];
    #pragma unroll
    for (int cc = 0; cc < 2; ++cc) {
      int cx = h * 2 + cc;
      int slot = cx ^ fsw;
      float4 v0 = rpA[kcs * 8 + cx * 2], v1 = rpA[kcs * 8 + cx * 2 + 1];
      u16x4 a0 = { f2bf(v0.x), f2bf(v0.y), f2bf(v0.z), f2bf(v0.w) };
      u16x4 a1 = { f2bf(v1.x), f2bf(v1.y), f2bf(v1.z), f2bf(v1.w) };
      *(u16x4*)&lA[row * BK + slot * 8]     = a0;
      *(u16x4*)&lA[row * BK + slot * 8 + 4] = a1;
      float4 w0 = rpB[kcs * 8 + cx * 2], w1 = rpB[kcs * 8 + cx * 2 + 1];
      u16x4 b0 = { f2bf(w0.x), f2bf(w0.y), f2bf(w0.z), f2bf(w0.w) };
      u16x4 b1 = { f2bf(w1.x), f2bf(w1.y), f2bf(w1.z), f2bf(w1.w) };
      *(u16x4*)&lB[row * BK + slot * 8]     = b0;
      *(u16x4*)&lB[row * BK + slot * 8 + 4] = b1;
    }
    __syncthreads();
    const unsigned short* Ab = As[kcs & 1];
    const unsigned short* Bb = Bs[kcs & 1];
    bf16x8 af[4], bfr[4];
    #pragma unroll
    for (int m = 0; m < 4; ++m)
      af[m] = *(const bf16x8*)&Ab[(wm * 64 + m * 16 + lr) * BK + coff];
    #pragma unroll
    for (int n = 0; n < 4; ++n)
      bfr[n] = *(const bf16x8*)&Bb[(wn * 64 + n * 16 + lr) * BK + coff];
    #pragma unroll
    for (int m = 0; m < 4; ++m)
      #pragma unroll
      for (int n = 0; n < 4; ++n)
        acc[m][n] = __builtin_amdgcn_mfma_f32_16x16x32_bf16(af[m], bfr[n], acc[m][n], 0, 0, 0);
  }

  float coef = ws->coef;
  float coef2 = 2.f * coef;
  int ibase = Ib + wm * 64;
  int jbase = Jb + wn * 64;
  float nscj[4];
  f32x2 nsci01[4], nsci23[4];
  #pragma unroll
  for (int n = 0; n < 4; ++n) nscj[n] = -ws->sq[jbase + n * 16 + lr] * coef;
  #pragma unroll
  for (int m = 0; m < 4; ++m) {
    nsci01[m] = f32x2{ -ws->sq[ibase + m * 16 + q * 4 + 0] * coef,
                       -ws->sq[ibase + m * 16 + q * 4 + 1] * coef };
    nsci23[m] = f32x2{ -ws->sq[ibase + m * 16 + q * 4 + 2] * coef,
                       -ws->sq[ibase + m * 16 + q * 4 + 3] * coef };
  }
  const f32x2 c2v = { coef2, coef2 };
  f32x2 accA = {0.f, 0.f}, accB = {0.f, 0.f};
  f32x2 accC = {0.f, 0.f}, accD = {0.f, 0.f};
  #pragma unroll
  for (int m = 0; m < 4; ++m) {
    #pragma unroll
    for (int n = 0; n < 4; ++n) {
      f32x4 g = acc[m][n];
      f32x2 bj = { nscj[n], nscj[n] };
      f32x2 b01 = nsci01[m] + bj;
      f32x2 b23 = nsci23[m] + bj;
      f32x2 a01 = f32x2{g[0], g[1]} * c2v + b01;
      f32x2 a23 = f32x2{g[2], g[3]} * c2v + b23;
      f32x2 t0, t1;
      t0.x = __builtin_amdgcn_exp2f(a01.x); t0.y = __builtin_amdgcn_exp2f(a01.y);
      t1.x = __builtin_amdgcn_exp2f(a23.x); t1.y = __builtin_amdgcn_exp2f(a23.y);
      f32x2 p0 = t0 * t0, p1 = t1 * t1;
      f32x2 q0 = p0 * p0, q1 = p1 * p1;
      f32x2 r0v = q0 * q0, r1v = q1 * q1;
      accA += t0 + p0;
      accB += q0 + r0v;
      accA = r0v * r0v + accA;
      accC += t1 + p1;
      accD += q1 + r1v;
      accC = r1v * r1v + accC;
    }
  }
  float lsum = (accA.x + accA.y) + (accB.x + accB.y)
             + (accC.x + accC.y) + (accD.x + accD.y);
  #pragma unroll
  for (int off = 32; off > 0; off >>= 1) lsum += __shfl_xor(lsum, off);
  if (lane == 0) wsum[wave] = lsum;
  __syncthreads();
  if (tid == 0) {
    float tot = wsum[0] + wsum[1] + wsum[2] + wsum[3];
    float sA = (ti < 32) ? 1.f : -1.f;
    float sB = (tj < 32) ? 1.f : -1.f;
    float fac = sA * sB * ((ti == tj) ? 1.f : 2.f);
    int slot = 64 * ti - (ti * (ti - 1)) / 2 + (tj - ti);
    ws->part[slot] = fac * tot;
  }
}

// 1 block x 256 threads: double-precision reduce of part[] -> out scalar.
__global__ __launch_bounds__(256) void k_final(const Ws* __restrict__ ws,
                                               float* __restrict__ out) {
  __shared__ double red[4];
  int tid = threadIdx.x, wave = tid >> 6, lane = tid & 63;
  double s = 0.0;
  for (int i = tid; i < NBLK; i += 256) s += (double)ws->part[i];
  #pragma unroll
  for (int off = 32; off > 0; off >>= 1) s += __shfl_xor(s, off);
  if (lane == 0) red[wave] = s;
  __syncthreads();
  if (tid == 0)
    out[0] = (float)((red[0] + red[1] + red[2] + red[3]) /
                     ((double)BHALF * (double)BHALF));
}

extern "C" void kernel_launch(void* const* d_in, const int* in_sizes, int n_in,
                              void* d_out, int out_size, void* d_ws, size_t ws_size,
                              hipStream_t stream) {
  const float* src = (const float*)d_in[0];
  const float* tgt = (const float*)d_in[1];
  Ws* ws = (Ws*)d_ws;
  float* out = (float*)d_out;

  size_t wsoff = (sizeof(Ws) + 255) & ~(size_t)255;
  size_t need = wsoff + (size_t)NROWS * DDIM * 2;
  bool fast = ws_size >= need;
  unsigned short* tb = fast ? (unsigned short*)((char*)d_ws + wsoff) : nullptr;

  hipLaunchKernelGGL(k_prep, dim3(256), dim3(256), 0, stream, src, tgt, ws, tb,
                     fast ? 1 : 0);
  hipLaunchKernelGGL(k_bw, dim3(1), dim3(256), 0, stream, ws);
  if (fast)
    hipLaunchKernelGGL(k_main2, dim3(NBLK2), dim3(512), 0, stream, tb, ws);
  else
    hipLaunchKernelGGL(k_main_slow, dim3(NBLK), dim3(256), 0, stream, src, tgt, ws);
  hipLaunchKernelGGL(k_final, dim3(1), dim3(256), 0, stream, ws, out);
}